// Round 13
// baseline (125.383 us; speedup 1.0000x reference)
//
#include <hip/hip_runtime.h>

#define HH 128
#define WW 128
#define CC 64
#define KD 16
#define HW (HH * WW)
#define HWB (HW * 4)
#define TOTBYTES (4u * CC * HW * 4u)   // B=4 * C=64 * H*W * 4B = 16.78 MB
#define OOB_SENT 0x40000000            // always-OOB voffset -> HW returns 0

typedef __attribute__((ext_vector_type(4))) int   int32x4_t;
typedef __attribute__((ext_vector_type(4))) float floatx4;
typedef __attribute__((ext_vector_type(2))) float floatx2;

__device__ floatx4 llvm_amdgcn_raw_buffer_load_v4f32(int32x4_t srsrc, int voffset,
                                                     int soffset, int aux)
    __asm("llvm.amdgcn.raw.buffer.load.v4f32");
__device__ floatx2 llvm_amdgcn_raw_buffer_load_v2f32(int32x4_t srsrc, int voffset,
                                                     int soffset, int aux)
    __asm("llvm.amdgcn.raw.buffer.load.v2f32");

__device__ inline int32x4_t make_srd(const void* p, unsigned bytes) {
    const unsigned long long a = (unsigned long long)p;
    int32x4_t r;
    r.x = (int)(a & 0xffffffffull);
    r.y = (int)(a >> 32);
    r.z = (int)bytes;
    r.w = 0x00020000;
    return r;
}

#if __has_builtin(__builtin_amdgcn_exp2f)
#define FAST_EXP2(x) __builtin_amdgcn_exp2f(x)
#define KLOG2E 1.44269504088896340736f
#else
#define FAST_EXP2(x) __expf(x)
#define KLOG2E 1.0f
#endif

// ---- pre-kernel: repack Wk [16][64][9] -> wsr [(c*9+t)*16 + d] -------------
__global__ __launch_bounds__(512, 1) void repack_wk(const float* __restrict__ Wk,
                                                    float* __restrict__ wsr) {
    const int e = blockIdx.x * 512 + threadIdx.x;    // 9216 total
    const int d = e & 15;
    const int r = e >> 4;
    const int t = r % 9;
    const int c = r / 9;
    wsr[e] = Wk[(d * CC + c) * 9 + t];
}

// Block: 1024 threads = 16 waves over one 32(w) x 4(h) pixel tile; each lane
// owns a horizontal pixel pair; wave g owns only 4 channels [4g, 4g+4).
// Occupancy: 2 blocks/CU x 16 waves = 32 waves/CU (vs R11's 16) -- the LDS
// partial buffer that forced 64 KB is replaced by ds_add_f32 atomic
// accumulation into k[16][128] (8 KB), so LDS no longer caps blocks/CU.
// Phase 1: partial k over 4 channels (packed v_pk_fma_f32, scalar weights
//          from repacked wsr) -> atomicAdd into k_lds.
// Phase 2: q-conv + v + softmax packed over the pixel pair, 4 channels.
__global__ __launch_bounds__(1024, 8) void gatev_fused(
    const float* __restrict__ x, const float* __restrict__ y,
    const float* __restrict__ z,
    const float* __restrict__ wsr,                    // repacked Wk
    const float* __restrict__ Wq, const float* __restrict__ bq,
    const float* __restrict__ bk,
    const float* __restrict__ wv, const float* __restrict__ bv,
    float* __restrict__ out)
{
    __shared__ float klds[KD * 128];   // 8 KB: k[d][p], atomically accumulated

    const int tid  = threadIdx.x;
    const int g    = __builtin_amdgcn_readfirstlane(tid >> 6);   // [0,16)
    const int lane = tid & 63;
    const int px16 = lane & 15, py = lane >> 4;
    const int b    = blockIdx.z;
    const int w0   = blockIdx.x * 32 + px16 * 2;   // even
    const int h    = blockIdx.y * 4 + py;
    const int pix  = h * WW + w0;
    const int p0   = py * 32 + px16 * 2;           // pixel-linear in tile

    const int32x4_t rx = make_srd(x, TOTBYTES);
    const int32x4_t ry = make_srd(y, TOTBYTES);
    const int32x4_t rz = make_srd(z, TOTBYTES);

    // One float4 per tap-row at col max(w0-1,0): covers cols w0-1..w0+2.
    const int colb = (w0 > 0 ? w0 - 1 : 0) * 4;
    int rowB[3];
#pragma unroll
    for (int r = 0; r < 3; ++r) {
        const int rr = h - 1 + r;
        rowB[r] = (rr >= 0 && rr < HH) ? rr * WW * 4 + colb : OOB_SENT;
    }
    const bool  intw = (blockIdx.x > 0) & (blockIdx.x < (WW / 32 - 1));
    const float mL = (w0 > 0) ? 1.f : 0.f;           // px0 left tap
    const float mR = (w0 + 2 < WW) ? 1.f : 0.f;      // px1 right tap
    const bool  w0e = (w0 == 0);

    const int base = b * CC * HWB;
    const int c0   = __builtin_amdgcn_readfirstlane(g * 4);

    // ---------------- zero-init k ------------------------------------------
    ((floatx2*)klds)[tid] = (floatx2){0.f, 0.f};     // 1024 x 8B = 8 KB
    __syncthreads();

    // 4 tap columns per row: s0 = w0-1, s1 = w0, s2 = w0+1, s3 = w0+2
    auto mktaps = [&](const floatx4& f, float (&s)[4]) {
        if (intw) { s[0] = f.x; s[1] = f.y; s[2] = f.z; s[3] = f.w; }
        else {
            s[0] = f.x * mL;
            s[1] = w0e ? f.x : f.y;
            s[2] = w0e ? f.y : f.z;
            s[3] = (w0e ? f.z : f.w) * mR;
        }
    };

    // ---------------- phase 1: packed partial k, 4 channels, 2 px ----------
    floatx2 aP0[8], aP1[8];                // [d-pair] per pixel
#pragma unroll
    for (int i = 0; i < 8; ++i) { aP0[i] = (floatx2){0.f, 0.f}; aP1[i] = (floatx2){0.f, 0.f}; }

    auto load3 = [&](floatx4 (&f)[3], int so) {
#pragma unroll
        for (int r = 0; r < 3; ++r)
            f[r] = llvm_amdgcn_raw_buffer_load_v4f32(rx, rowB[r], so, 0);
    };
    auto compute = [&](const floatx4 (&f)[3], const float* wp) {
        float s[3][4];
#pragma unroll
        for (int r = 0; r < 3; ++r) mktaps(f[r], s[r]);
#pragma unroll
        for (int t = 0; t < 9; ++t) {
            const int tr = t / 3, tc = t % 3;
            const floatx2 t0 = {s[tr][tc],     s[tr][tc]};
            const floatx2 t1 = {s[tr][tc + 1], s[tr][tc + 1]};
#pragma unroll
            for (int j = 0; j < 4; ++j) {    // uniform -> s_load (SMEM pipe)
                const floatx4 w4 = *(const floatx4*)&wp[t * 16 + j * 4];
                const floatx2 lo = __builtin_shufflevector(w4, w4, 0, 1);
                const floatx2 hi = __builtin_shufflevector(w4, w4, 2, 3);
                aP0[2 * j + 0] = __builtin_elementwise_fma(lo, t0, aP0[2 * j + 0]);
                aP0[2 * j + 1] = __builtin_elementwise_fma(hi, t0, aP0[2 * j + 1]);
                aP1[2 * j + 0] = __builtin_elementwise_fma(lo, t1, aP1[2 * j + 0]);
                aP1[2 * j + 1] = __builtin_elementwise_fma(hi, t1, aP1[2 * j + 1]);
            }
        }
    };

    {
        floatx4 f0[3], f1[3];
        load3(f0, base + c0 * HWB);
#pragma unroll
        for (int cp = 0; cp < 2; ++cp) {
            load3(f1, base + (c0 + 2 * cp + 1) * HWB);       // prefetch odd channel
            compute(f0, wsr + (c0 + 2 * cp) * 144);
            load3(f0, base + (c0 + 2 * cp + 2) * HWB);       // prefetch next even (tail SRD-bounded)
            compute(f1, wsr + (c0 + 2 * cp + 1) * 144);
        }
    }

    // atomic accumulate partials into k[d][p]  (ds_add_f32; 2-way bank alias)
#pragma unroll
    for (int i = 0; i < 8; ++i) {
        atomicAdd(&klds[(2 * i + 0) * 128 + p0],     aP0[i].x);
        atomicAdd(&klds[(2 * i + 0) * 128 + p0 + 1], aP1[i].x);
        atomicAdd(&klds[(2 * i + 1) * 128 + p0],     aP0[i].y);
        atomicAdd(&klds[(2 * i + 1) * 128 + p0 + 1], aP1[i].y);
    }
    __syncthreads();

    // ---------------- bias + relu + log2e (in place) ------------------------
#pragma unroll
    for (int rep = 0; rep < 2; ++rep) {
        const int idx = tid + rep * 1024;                // = d*128 + p
        const int d   = idx >> 7;                        // wave-uniform
        klds[idx] = fmaxf(klds[idx] + bk[d], 0.f) * KLOG2E;
    }
    __syncthreads();

    // ---------------- phase 2: q, v, softmax, packed over pixel pair --------
    floatx2 kl2[16];                                     // k for both pixels, hoisted
#pragma unroll
    for (int d = 0; d < KD; ++d)
        kl2[d] = *(const floatx2*)&klds[d * 128 + p0];

    auto process = [&](const floatx4 (&f)[3], floatx2 z2, int c) {
        const float* wq = Wq + c * 9;                    // uniform -> s_load
        float s[3][4];
#pragma unroll
        for (int r = 0; r < 3; ++r) mktaps(f[r], s[r]);
        floatx2 q2 = {bq[c], bq[c]};
#pragma unroll
        for (int t = 0; t < 9; ++t) {
            const int tr = t / 3, tc = t % 3;
            const floatx2 tp2 = {s[tr][tc], s[tr][tc + 1]};
            const floatx2 wq2 = {wq[t], wq[t]};
            q2 = __builtin_elementwise_fma(wq2, tp2, q2);
        }
        const floatx2 zero2 = {0.f, 0.f};
        q2 = __builtin_elementwise_max(q2, zero2);

        floatx2 num2 = zero2, den2 = zero2;
#pragma unroll
        for (int d = 0; d < KD; ++d) {
            const floatx2 s2 = q2 * kl2[d];              // v_pk_mul_f32
            floatx2 e2;
            e2.x = FAST_EXP2(s2.x);
            e2.y = FAST_EXP2(s2.y);
            const floatx2 wv2 = {wv[d], wv[d]};
            const floatx2 bv2 = {bv[d], bv[d]};
            const floatx2 v2 = __builtin_elementwise_max(
                __builtin_elementwise_fma(z2, wv2, bv2), zero2);
            num2 = __builtin_elementwise_fma(e2, v2, num2);
            den2 = den2 + e2;
        }
        floatx2 o2;
        o2.x = __fdividef(num2.x, den2.x);
        o2.y = __fdividef(num2.y, den2.y);
        *(floatx2*)&out[(size_t)b * CC * HW + (size_t)c * HW + pix] = o2;
    };

    auto load3y = [&](floatx4 (&f)[3], floatx2& zz, int so) {
#pragma unroll
        for (int r = 0; r < 3; ++r)
            f[r] = llvm_amdgcn_raw_buffer_load_v4f32(ry, rowB[r], so, 0);
        zz = llvm_amdgcn_raw_buffer_load_v2f32(rz, pix * 4, so, 0);
    };

    {
        floatx4 fy0[3], fy1[3];
        floatx2 z0, z1;
        load3y(fy0, z0, base + c0 * HWB);
#pragma unroll
        for (int cp = 0; cp < 2; ++cp) {
            load3y(fy1, z1, base + (c0 + 2 * cp + 1) * HWB);
            process(fy0, z0, c0 + 2 * cp);
            load3y(fy0, z0, base + (c0 + 2 * cp + 2) * HWB); // tail SRD-bounded
            process(fy1, z1, c0 + 2 * cp + 1);
        }
    }
}

extern "C" void kernel_launch(void* const* d_in, const int* in_sizes, int n_in,
                              void* d_out, int out_size, void* d_ws, size_t ws_size,
                              hipStream_t stream) {
    const float* x  = (const float*)d_in[0];
    const float* y  = (const float*)d_in[1];
    const float* z  = (const float*)d_in[2];
    const float* Wq = (const float*)d_in[3];
    const float* bq = (const float*)d_in[4];
    const float* Wk = (const float*)d_in[5];
    const float* bk = (const float*)d_in[6];
    const float* wv = (const float*)d_in[7];
    const float* bv = (const float*)d_in[8];
    float* out = (float*)d_out;
    float* wsr = (float*)d_ws;                       // 36864 B of scratch

    hipLaunchKernelGGL(repack_wk, dim3(18), dim3(512), 0, stream, Wk, wsr);

    dim3 grid(WW / 32, HH / 4, 4);   // (4, 32, 4) = 512 blocks = 2/CU
    dim3 block(1024);                // 16 waves
    hipLaunchKernelGGL(gatev_fused, grid, block, 0, stream,
                       x, y, z, wsr, Wq, bq, bk, wv, bv, out);
}

// Round 14
// 84.946 us; speedup vs baseline: 1.4760x; 1.4760x over previous
//
#include <hip/hip_runtime.h>

#define HH 128
#define WW 128
#define CC 64
#define KD 16
#define HW (HH * WW)
#define HWB (HW * 4)
#define TOTBYTES (4u * CC * HW * 4u)   // B=4 * C=64 * H*W * 4B = 16.78 MB
#define OOB_SENT 0x40000000            // always-OOB voffset -> HW returns 0

typedef __attribute__((ext_vector_type(4))) int   int32x4_t;
typedef __attribute__((ext_vector_type(4))) float floatx4;
typedef __attribute__((ext_vector_type(2))) float floatx2;

__device__ floatx4 llvm_amdgcn_raw_buffer_load_v4f32(int32x4_t srsrc, int voffset,
                                                     int soffset, int aux)
    __asm("llvm.amdgcn.raw.buffer.load.v4f32");
__device__ floatx2 llvm_amdgcn_raw_buffer_load_v2f32(int32x4_t srsrc, int voffset,
                                                     int soffset, int aux)
    __asm("llvm.amdgcn.raw.buffer.load.v2f32");

__device__ inline int32x4_t make_srd(const void* p, unsigned bytes) {
    const unsigned long long a = (unsigned long long)p;
    int32x4_t r;
    r.x = (int)(a & 0xffffffffull);
    r.y = (int)(a >> 32);
    r.z = (int)bytes;
    r.w = 0x00020000;
    return r;
}

#if __has_builtin(__builtin_amdgcn_exp2f)
#define FAST_EXP2(x) __builtin_amdgcn_exp2f(x)
#define KLOG2E 1.44269504088896340736f
#else
#define FAST_EXP2(x) __expf(x)
#define KLOG2E 1.0f
#endif

// ---- pre-kernel: repack Wk [16][64][9] -> wsr [(c*9+t)*16 + d] -------------
__global__ __launch_bounds__(512, 1) void repack_wk(const float* __restrict__ Wk,
                                                    float* __restrict__ wsr) {
    const int e = blockIdx.x * 512 + threadIdx.x;    // 9216 total
    const int d = e & 15;
    const int r = e >> 4;
    const int t = r % 9;
    const int c = r / 9;
    wsr[e] = Wk[(d * CC + c) * 9 + t];
}

// Block: 1024 threads = 16 waves over one 32(w) x 4(h) pixel tile; each lane
// owns a horizontal pixel pair; wave g owns 4 channels [4g, 4g+4).
// Occupancy: 2 blocks/CU x 16 waves = 32 waves/CU (LDS 64 KB x 2 = 128 <= 160,
// VGPR <= 64 via launch_bounds). The R13 atomic disaster is replaced by a
// contention-free two-round partial accumulation in ordinary LDS:
//   round A: waves 0-7 WRITE slabs [g][16d][128p]      (64 KB)
//   round B: waves 8-15 read-add-write slab (g-8)      (disjoint addresses)
//   then the proven 8-way tree reduce + bias/relu/log2e.
// Weights: scalar s_loads from repacked wsr (2.3 KB/wave, K$-resident).
// Phase 2: q-conv + v + packed softmax over the pixel pair, 4 channels/wave.
__global__ __launch_bounds__(1024, 8) void gatev_fused(
    const float* __restrict__ x, const float* __restrict__ y,
    const float* __restrict__ z,
    const float* __restrict__ wsr,                    // repacked Wk
    const float* __restrict__ Wq, const float* __restrict__ bq,
    const float* __restrict__ bk,
    const float* __restrict__ wv, const float* __restrict__ bv,
    float* __restrict__ out)
{
    __shared__ float lds[16384];   // 64 KB: 8 partial slabs -> k (aliased)

    const int tid  = threadIdx.x;
    const int g    = __builtin_amdgcn_readfirstlane(tid >> 6);   // [0,16)
    const int lane = tid & 63;
    const int px16 = lane & 15, py = lane >> 4;
    const int b    = blockIdx.z;
    const int w0   = blockIdx.x * 32 + px16 * 2;   // even
    const int h    = blockIdx.y * 4 + py;
    const int pix  = h * WW + w0;
    const int p0   = py * 32 + px16 * 2;           // pixel-linear in tile

    const int32x4_t rx = make_srd(x, TOTBYTES);
    const int32x4_t ry = make_srd(y, TOTBYTES);
    const int32x4_t rz = make_srd(z, TOTBYTES);

    // One float4 per tap-row at col max(w0-1,0): covers cols w0-1..w0+2.
    const int colb = (w0 > 0 ? w0 - 1 : 0) * 4;
    int rowB[3];
#pragma unroll
    for (int r = 0; r < 3; ++r) {
        const int rr = h - 1 + r;
        rowB[r] = (rr >= 0 && rr < HH) ? rr * WW * 4 + colb : OOB_SENT;
    }
    const bool  intw = (blockIdx.x > 0) & (blockIdx.x < (WW / 32 - 1));
    const float mL = (w0 > 0) ? 1.f : 0.f;           // px0 left tap
    const float mR = (w0 + 2 < WW) ? 1.f : 0.f;      // px1 right tap
    const bool  w0e = (w0 == 0);

    const int base = b * CC * HWB;
    const int c0   = __builtin_amdgcn_readfirstlane(g * 4);

    // 4 tap columns per row: s0 = w0-1, s1 = w0, s2 = w0+1, s3 = w0+2
    auto mktaps = [&](const floatx4& f, float (&s)[4]) {
        if (intw) { s[0] = f.x; s[1] = f.y; s[2] = f.z; s[3] = f.w; }
        else {
            s[0] = f.x * mL;
            s[1] = w0e ? f.x : f.y;
            s[2] = w0e ? f.y : f.z;
            s[3] = (w0e ? f.z : f.w) * mR;
        }
    };

    // ---------------- phase 1: packed partial k, 4 channels, 2 px ----------
    floatx2 aP0[8], aP1[8];                // [d-pair] per pixel
#pragma unroll
    for (int i = 0; i < 8; ++i) { aP0[i] = (floatx2){0.f, 0.f}; aP1[i] = (floatx2){0.f, 0.f}; }

    auto load3 = [&](floatx4 (&f)[3], int so) {
#pragma unroll
        for (int r = 0; r < 3; ++r)
            f[r] = llvm_amdgcn_raw_buffer_load_v4f32(rx, rowB[r], so, 0);
    };
    auto compute = [&](const floatx4 (&f)[3], const float* wp) {
        float s[3][4];
#pragma unroll
        for (int r = 0; r < 3; ++r) mktaps(f[r], s[r]);
#pragma unroll
        for (int t = 0; t < 9; ++t) {
            const int tr = t / 3, tc = t % 3;
            const floatx2 t0 = {s[tr][tc],     s[tr][tc]};
            const floatx2 t1 = {s[tr][tc + 1], s[tr][tc + 1]};
#pragma unroll
            for (int j = 0; j < 4; ++j) {    // uniform -> s_load (SMEM pipe)
                const floatx4 w4 = *(const floatx4*)&wp[t * 16 + j * 4];
                const floatx2 lo = __builtin_shufflevector(w4, w4, 0, 1);
                const floatx2 hi = __builtin_shufflevector(w4, w4, 2, 3);
                aP0[2 * j + 0] = __builtin_elementwise_fma(lo, t0, aP0[2 * j + 0]);
                aP0[2 * j + 1] = __builtin_elementwise_fma(hi, t0, aP0[2 * j + 1]);
                aP1[2 * j + 0] = __builtin_elementwise_fma(lo, t1, aP1[2 * j + 0]);
                aP1[2 * j + 1] = __builtin_elementwise_fma(hi, t1, aP1[2 * j + 1]);
            }
        }
    };

    {
        floatx4 f0[3], f1[3];
        load3(f0, base + c0 * HWB);
#pragma unroll
        for (int cp = 0; cp < 2; ++cp) {
            load3(f1, base + (c0 + 2 * cp + 1) * HWB);       // prefetch odd channel
            compute(f0, wsr + (c0 + 2 * cp) * 144);
            load3(f0, base + (c0 + 2 * cp + 2) * HWB);       // prefetch next even (tail SRD-bounded)
            compute(f1, wsr + (c0 + 2 * cp + 1) * 144);
        }
    }

    // ---- round A: waves 0-7 write partial slabs [g][d][p] ------------------
    if (g < 8) {
#pragma unroll
        for (int i = 0; i < 8; ++i) {
            *(floatx2*)&lds[g * 2048 + (2 * i + 0) * 128 + p0] = (floatx2){aP0[i].x, aP1[i].x};
            *(floatx2*)&lds[g * 2048 + (2 * i + 1) * 128 + p0] = (floatx2){aP0[i].y, aP1[i].y};
        }
    }
    __syncthreads();

    // ---- round B: waves 8-15 accumulate into slab (g-8) (disjoint addrs) ---
    if (g >= 8) {
        const int sb = (g - 8) * 2048;
#pragma unroll
        for (int i = 0; i < 8; ++i) {
            floatx2* a0 = (floatx2*)&lds[sb + (2 * i + 0) * 128 + p0];
            floatx2* a1 = (floatx2*)&lds[sb + (2 * i + 1) * 128 + p0];
            const floatx2 v0 = *a0 + (floatx2){aP0[i].x, aP1[i].x};
            const floatx2 v1 = *a1 + (floatx2){aP0[i].y, aP1[i].y};
            *a0 = v0;
            *a1 = v1;
        }
    }
    __syncthreads();

    // ---------------- reduce 8 slabs -> k[d][p] (in place, slab 0) ----------
#pragma unroll
    for (int rep = 0; rep < 2; ++rep) {
        const int idx = tid + rep * 1024;                // = d*128 + p
        float s = lds[idx];
#pragma unroll
        for (int gg = 1; gg < 8; ++gg) s += lds[gg * 2048 + idx];
        const int d = idx >> 7;                          // wave-uniform
        lds[idx] = fmaxf(s + bk[d], 0.f) * KLOG2E;
    }
    __syncthreads();

    // ---------------- phase 2: q, v, softmax, packed over pixel pair --------
    floatx2 kl2[16];                                     // k for both pixels
#pragma unroll
    for (int d = 0; d < KD; ++d)
        kl2[d] = *(const floatx2*)&lds[d * 128 + p0];

    auto process = [&](const floatx4 (&f)[3], floatx2 z2, int c) {
        const float* wq = Wq + c * 9;                    // uniform -> s_load
        float s[3][4];
#pragma unroll
        for (int r = 0; r < 3; ++r) mktaps(f[r], s[r]);
        floatx2 q2 = {bq[c], bq[c]};
#pragma unroll
        for (int t = 0; t < 9; ++t) {
            const int tr = t / 3, tc = t % 3;
            const floatx2 tp2 = {s[tr][tc], s[tr][tc + 1]};
            const floatx2 wq2 = {wq[t], wq[t]};
            q2 = __builtin_elementwise_fma(wq2, tp2, q2);
        }
        const floatx2 zero2 = {0.f, 0.f};
        q2 = __builtin_elementwise_max(q2, zero2);

        floatx2 num2 = zero2, den2 = zero2;
#pragma unroll
        for (int d = 0; d < KD; ++d) {
            const floatx2 s2 = q2 * kl2[d];              // v_pk_mul_f32
            floatx2 e2;
            e2.x = FAST_EXP2(s2.x);
            e2.y = FAST_EXP2(s2.y);
            const floatx2 wv2 = {wv[d], wv[d]};
            const floatx2 bv2 = {bv[d], bv[d]};
            const floatx2 v2 = __builtin_elementwise_max(
                __builtin_elementwise_fma(z2, wv2, bv2), zero2);
            num2 = __builtin_elementwise_fma(e2, v2, num2);
            den2 = den2 + e2;
        }
        floatx2 o2;
        o2.x = __fdividef(num2.x, den2.x);
        o2.y = __fdividef(num2.y, den2.y);
        *(floatx2*)&out[(size_t)b * CC * HW + (size_t)c * HW + pix] = o2;
    };

    auto load3y = [&](floatx4 (&f)[3], floatx2& zz, int so) {
#pragma unroll
        for (int r = 0; r < 3; ++r)
            f[r] = llvm_amdgcn_raw_buffer_load_v4f32(ry, rowB[r], so, 0);
        zz = llvm_amdgcn_raw_buffer_load_v2f32(rz, pix * 4, so, 0);
    };

    {
        floatx4 fy0[3], fy1[3];
        floatx2 z0, z1;
        load3y(fy0, z0, base + c0 * HWB);
#pragma unroll
        for (int cp = 0; cp < 2; ++cp) {
            load3y(fy1, z1, base + (c0 + 2 * cp + 1) * HWB);
            process(fy0, z0, c0 + 2 * cp);
            load3y(fy0, z0, base + (c0 + 2 * cp + 2) * HWB); // tail SRD-bounded
            process(fy1, z1, c0 + 2 * cp + 1);
        }
    }
}

extern "C" void kernel_launch(void* const* d_in, const int* in_sizes, int n_in,
                              void* d_out, int out_size, void* d_ws, size_t ws_size,
                              hipStream_t stream) {
    const float* x  = (const float*)d_in[0];
    const float* y  = (const float*)d_in[1];
    const float* z  = (const float*)d_in[2];
    const float* Wq = (const float*)d_in[3];
    const float* bq = (const float*)d_in[4];
    const float* Wk = (const float*)d_in[5];
    const float* bk = (const float*)d_in[6];
    const float* wv = (const float*)d_in[7];
    const float* bv = (const float*)d_in[8];
    float* out = (float*)d_out;
    float* wsr = (float*)d_ws;                       // 36864 B of scratch

    hipLaunchKernelGGL(repack_wk, dim3(18), dim3(512), 0, stream, Wk, wsr);

    dim3 grid(WW / 32, HH / 4, 4);   // (4, 32, 4) = 512 blocks = 2/CU
    dim3 block(1024);                // 16 waves
    hipLaunchKernelGGL(gatev_fused, grid, block, 0, stream,
                       x, y, z, wsr, Wq, bq, bk, wv, bv, out);
}

// Round 15
// 48.206 us; speedup vs baseline: 2.6010x; 1.7622x over previous
//
#include <hip/hip_runtime.h>

#define HH 128
#define WW 128
#define CC 64
#define KD 16
#define HW (HH * WW)
#define HWB (HW * 4)
#define TOTBYTES (4u * CC * HW * 4u)   // B=4 * C=64 * H*W * 4B = 16.78 MB
#define OOB_SENT 0x40000000            // always-OOB voffset -> HW returns 0

typedef __attribute__((ext_vector_type(4))) int   int32x4_t;
typedef __attribute__((ext_vector_type(4))) float floatx4;
typedef __attribute__((ext_vector_type(2))) float floatx2;

__device__ floatx4 llvm_amdgcn_raw_buffer_load_v4f32(int32x4_t srsrc, int voffset,
                                                     int soffset, int aux)
    __asm("llvm.amdgcn.raw.buffer.load.v4f32");
__device__ floatx2 llvm_amdgcn_raw_buffer_load_v2f32(int32x4_t srsrc, int voffset,
                                                     int soffset, int aux)
    __asm("llvm.amdgcn.raw.buffer.load.v2f32");

__device__ inline int32x4_t make_srd(const void* p, unsigned bytes) {
    const unsigned long long a = (unsigned long long)p;
    int32x4_t r;
    r.x = (int)(a & 0xffffffffull);
    r.y = (int)(a >> 32);
    r.z = (int)bytes;
    r.w = 0x00020000;
    return r;
}

#if __has_builtin(__builtin_amdgcn_exp2f)
#define FAST_EXP2(x) __builtin_amdgcn_exp2f(x)
#define KLOG2E 1.44269504088896340736f
#else
#define FAST_EXP2(x) __expf(x)
#define KLOG2E 1.0f
#endif

// ---- pre-kernel: repack Wk [16][64][9] -> wsr [(c*9+t)*16 + d] -------------
__global__ __launch_bounds__(512, 1) void repack_wk(const float* __restrict__ Wk,
                                                    float* __restrict__ wsr) {
    const int e = blockIdx.x * 512 + threadIdx.x;    // 9216 total
    const int d = e & 15;
    const int r = e >> 4;
    const int t = r % 9;
    const int c = r / 9;
    wsr[e] = Wk[(d * CC + c) * 9 + t];
}

// Block: 512 threads = 8 waves over one 32(w) x 4(h) pixel tile; each lane
// owns a horizontal pixel pair; wave g owns channels [8g, 8g+8).
// KEY CHANGE vs R12: amdgpu_waves_per_eu(4,4). LDS (64 KB) caps residency at
// 2 blocks/CU = 4 waves/SIMD, but the compiler's default VGPR heuristic for
// 512-thr blocks pinned VGPR=64 (8-waves target), forcing serial
// load->compute per channel. Declaring the true residency frees 128 VGPR so
// the scheduler can hold 2 channels of buffers + accumulators live.
// Also: phase-2's first two channels of y/z loads are issued BEFORE the
// partial-store barriers (latency hidden under store+reduce).
__global__ __launch_bounds__(512)
__attribute__((amdgpu_waves_per_eu(4, 4))) void gatev_fused(
    const float* __restrict__ x, const float* __restrict__ y,
    const float* __restrict__ z,
    const float* __restrict__ wsr,                    // repacked Wk
    const float* __restrict__ Wq, const float* __restrict__ bq,
    const float* __restrict__ bk,
    const float* __restrict__ wv, const float* __restrict__ bv,
    float* __restrict__ out)
{
    __shared__ float lds[16384];   // 64 KB: partials -> k (aliased)

    const int tid  = threadIdx.x;
    const int g    = __builtin_amdgcn_readfirstlane(tid >> 6);
    const int lane = tid & 63;
    const int px16 = lane & 15, py = lane >> 4;
    const int b    = blockIdx.z;
    const int w0   = blockIdx.x * 32 + px16 * 2;   // even
    const int h    = blockIdx.y * 4 + py;
    const int pix  = h * WW + w0;
    const int p0   = py * 32 + px16 * 2;           // pixel-linear in tile

    const int32x4_t rx = make_srd(x, TOTBYTES);
    const int32x4_t ry = make_srd(y, TOTBYTES);
    const int32x4_t rz = make_srd(z, TOTBYTES);

    // One float4 per tap-row at col max(w0-1,0): covers cols w0-1..w0+2.
    const int colb = (w0 > 0 ? w0 - 1 : 0) * 4;
    int rowB[3];
#pragma unroll
    for (int r = 0; r < 3; ++r) {
        const int rr = h - 1 + r;
        rowB[r] = (rr >= 0 && rr < HH) ? rr * WW * 4 + colb : OOB_SENT;
    }
    const bool  intw = (blockIdx.x > 0) & (blockIdx.x < (WW / 32 - 1));
    const float mL = (w0 > 0) ? 1.f : 0.f;           // px0 left tap
    const float mR = (w0 + 2 < WW) ? 1.f : 0.f;      // px1 right tap
    const bool  w0e = (w0 == 0);

    const int base = b * CC * HWB;
    const int c0   = __builtin_amdgcn_readfirstlane(g * 8);

    // 4 tap columns per row: s0 = w0-1, s1 = w0, s2 = w0+1, s3 = w0+2
    auto mktaps = [&](const floatx4& f, float (&s)[4]) {
        if (intw) { s[0] = f.x; s[1] = f.y; s[2] = f.z; s[3] = f.w; }
        else {
            s[0] = f.x * mL;
            s[1] = w0e ? f.x : f.y;
            s[2] = w0e ? f.y : f.z;
            s[3] = (w0e ? f.z : f.w) * mR;
        }
    };

    // ---------------- phase 1: packed partial k, 8 channels, 2 px ----------
    floatx2 aP0[8], aP1[8];                // [d-pair] per pixel
#pragma unroll
    for (int i = 0; i < 8; ++i) { aP0[i] = (floatx2){0.f, 0.f}; aP1[i] = (floatx2){0.f, 0.f}; }

    auto load3 = [&](floatx4 (&f)[3], int so) {
#pragma unroll
        for (int r = 0; r < 3; ++r)
            f[r] = llvm_amdgcn_raw_buffer_load_v4f32(rx, rowB[r], so, 0);
    };
    auto compute = [&](const floatx4 (&f)[3], const float* wp) {
        float s[3][4];
#pragma unroll
        for (int r = 0; r < 3; ++r) mktaps(f[r], s[r]);
#pragma unroll
        for (int t = 0; t < 9; ++t) {
            const int tr = t / 3, tc = t % 3;
            const floatx2 t0 = {s[tr][tc],     s[tr][tc]};
            const floatx2 t1 = {s[tr][tc + 1], s[tr][tc + 1]};
#pragma unroll
            for (int j = 0; j < 4; ++j) {    // uniform -> s_load (SMEM pipe)
                const floatx4 w4 = *(const floatx4*)&wp[t * 16 + j * 4];
                const floatx2 lo = __builtin_shufflevector(w4, w4, 0, 1);
                const floatx2 hi = __builtin_shufflevector(w4, w4, 2, 3);
                aP0[2 * j + 0] = __builtin_elementwise_fma(lo, t0, aP0[2 * j + 0]);
                aP0[2 * j + 1] = __builtin_elementwise_fma(hi, t0, aP0[2 * j + 1]);
                aP1[2 * j + 0] = __builtin_elementwise_fma(lo, t1, aP1[2 * j + 0]);
                aP1[2 * j + 1] = __builtin_elementwise_fma(hi, t1, aP1[2 * j + 1]);
            }
        }
    };

    {
        floatx4 f0[3], f1[3];
        load3(f0, base + c0 * HWB);
#pragma unroll
        for (int cp = 0; cp < 4; ++cp) {
            load3(f1, base + (c0 + 2 * cp + 1) * HWB);       // prefetch odd channel
            compute(f0, wsr + (c0 + 2 * cp) * 144);
            load3(f0, base + (c0 + 2 * cp + 2) * HWB);       // prefetch next even (tail SRD-bounded)
            compute(f1, wsr + (c0 + 2 * cp + 1) * 144);
        }
    }

    // ---- early phase-2 prefetch: first 2 channels of y + z ------------------
    auto load3y = [&](floatx4 (&f)[3], floatx2& zz, int so) {
#pragma unroll
        for (int r = 0; r < 3; ++r)
            f[r] = llvm_amdgcn_raw_buffer_load_v4f32(ry, rowB[r], so, 0);
        zz = llvm_amdgcn_raw_buffer_load_v2f32(rz, pix * 4, so, 0);
    };
    floatx4 fy0[3], fy1[3];
    floatx2 z0, z1;
    load3y(fy0, z0, base + (c0 + 0) * HWB);   // latency hidden under store+reduce
    load3y(fy1, z1, base + (c0 + 1) * HWB);

    // partials [g][d][p]: (p0, p0+1) contiguous -> b64 writes
#pragma unroll
    for (int i = 0; i < 8; ++i) {
        *(floatx2*)&lds[g * 2048 + (2 * i + 0) * 128 + p0] = (floatx2){aP0[i].x, aP1[i].x};
        *(floatx2*)&lds[g * 2048 + (2 * i + 1) * 128 + p0] = (floatx2){aP0[i].y, aP1[i].y};
    }
    __syncthreads();

    // ---------------- reduce 8 partials -> k[d][p] (in place) ---------------
#pragma unroll
    for (int rep = 0; rep < 4; ++rep) {
        const int idx = tid + rep * 512;                 // = d*128 + p
        float s = lds[idx];
#pragma unroll
        for (int gg = 1; gg < 8; ++gg) s += lds[gg * 2048 + idx];
        const int d = idx >> 7;                          // wave-uniform
        lds[idx] = fmaxf(s + bk[d], 0.f) * KLOG2E;
    }
    __syncthreads();

    // ---------------- phase 2: q, v, softmax, packed over pixel pair --------
    floatx2 kl2[16];                                     // k for both pixels, hoisted
#pragma unroll
    for (int d = 0; d < KD; ++d)
        kl2[d] = *(const floatx2*)&lds[d * 128 + p0];

    auto process = [&](const floatx4 (&f)[3], floatx2 z2, int c) {
        const float* wq = Wq + c * 9;                    // uniform -> s_load
        float s[3][4];
#pragma unroll
        for (int r = 0; r < 3; ++r) mktaps(f[r], s[r]);
        floatx2 q2 = {bq[c], bq[c]};
#pragma unroll
        for (int t = 0; t < 9; ++t) {
            const int tr = t / 3, tc = t % 3;
            const floatx2 tp2 = {s[tr][tc], s[tr][tc + 1]};
            const floatx2 wq2 = {wq[t], wq[t]};
            q2 = __builtin_elementwise_fma(wq2, tp2, q2);
        }
        const floatx2 zero2 = {0.f, 0.f};
        q2 = __builtin_elementwise_max(q2, zero2);

        floatx2 num2 = zero2, den2 = zero2;
#pragma unroll
        for (int d = 0; d < KD; ++d) {
            const floatx2 s2 = q2 * kl2[d];              // v_pk_mul_f32
            floatx2 e2;
            e2.x = FAST_EXP2(s2.x);
            e2.y = FAST_EXP2(s2.y);
            const floatx2 wv2 = {wv[d], wv[d]};
            const floatx2 bv2 = {bv[d], bv[d]};
            const floatx2 v2 = __builtin_elementwise_max(
                __builtin_elementwise_fma(z2, wv2, bv2), zero2);
            num2 = __builtin_elementwise_fma(e2, v2, num2);
            den2 = den2 + e2;
        }
        floatx2 o2;
        o2.x = __fdividef(num2.x, den2.x);
        o2.y = __fdividef(num2.y, den2.y);
        *(floatx2*)&out[(size_t)b * CC * HW + (size_t)c * HW + pix] = o2;
    };

    // 2-channel prefetch distance through the loop (buffers loaded pre-barrier)
#pragma unroll
    for (int cp = 0; cp < 4; ++cp) {
        process(fy0, z0, c0 + 2 * cp);
        if (cp < 3) load3y(fy0, z0, base + (c0 + 2 * cp + 2) * HWB);
        process(fy1, z1, c0 + 2 * cp + 1);
        if (cp < 3) load3y(fy1, z1, base + (c0 + 2 * cp + 3) * HWB);
    }
}

extern "C" void kernel_launch(void* const* d_in, const int* in_sizes, int n_in,
                              void* d_out, int out_size, void* d_ws, size_t ws_size,
                              hipStream_t stream) {
    const float* x  = (const float*)d_in[0];
    const float* y  = (const float*)d_in[1];
    const float* z  = (const float*)d_in[2];
    const float* Wq = (const float*)d_in[3];
    const float* bq = (const float*)d_in[4];
    const float* Wk = (const float*)d_in[5];
    const float* bk = (const float*)d_in[6];
    const float* wv = (const float*)d_in[7];
    const float* bv = (const float*)d_in[8];
    float* out = (float*)d_out;
    float* wsr = (float*)d_ws;                       // 36864 B of scratch

    hipLaunchKernelGGL(repack_wk, dim3(18), dim3(512), 0, stream, Wk, wsr);

    dim3 grid(WW / 32, HH / 4, 4);   // (4, 32, 4) = 512 blocks = 2/CU
    dim3 block(512);                 // 8 waves
    hipLaunchKernelGGL(gatev_fused, grid, block, 0, stream,
                       x, y, z, wsr, Wq, bq, bk, wv, bv, out);
}